// Round 1
// baseline (789.769 us; speedup 1.0000x reference)
//
#include <hip/hip_runtime.h>

#define NN 100000
#define DIN 128

__device__ __forceinline__ void atomAddF(float* p, float v) {
    // HW global_atomic_add_f32 (coarse-grained device memory -> safe here).
    unsafeAtomicAdd(p, v);
}

// 1) in-degree of targets (self-loop +1 added later)
__global__ __launch_bounds__(256) void deg_kernel(const int* __restrict__ col,
                                                  float* __restrict__ deg, int E) {
    int e = blockIdx.x * 256 + threadIdx.x;
    if (e < E) atomAddF(&deg[col[e]], 1.0f);
}

// 2) dis = rsqrt(deg + 1)  (in place)
__global__ __launch_bounds__(256) void dis_kernel(float* __restrict__ deg, int N) {
    int i = blockIdx.x * 256 + threadIdx.x;
    if (i < N) deg[i] = rsqrtf(deg[i] + 1.0f);
}

// 3) h = x @ W1   [N,128]x[128,16] -> [N,16]
//    block = 256 threads = 16 nodes x 16 outputs; x tile + W1 staged in LDS.
__global__ __launch_bounds__(256) void xw1_kernel(const float* __restrict__ x,
                                                  const float* __restrict__ W1,
                                                  float* __restrict__ h, int N) {
    __shared__ float ws[DIN * 16];      // W1[d][k] at d*16+k
    __shared__ float xs[16 * 129];      // 16 rows, padded stride 129 (bank spread)
    int base = blockIdx.x * 16;
    for (int i = threadIdx.x; i < DIN * 16; i += 256) ws[i] = W1[i];
    for (int i = threadIdx.x; i < 16 * DIN; i += 256) {
        int nd = i >> 7, d = i & 127;
        int n = base + nd;
        xs[nd * 129 + d] = (n < N) ? x[(size_t)n * DIN + d] : 0.0f;
    }
    __syncthreads();
    int nd = threadIdx.x >> 4;
    int k  = threadIdx.x & 15;
    int n  = base + nd;
    if (n >= N) return;
    const float* xr = xs + nd * 129;
    float acc = 0.0f;
    #pragma unroll
    for (int d = 0; d < DIN; d++) acc = fmaf(xr[d], ws[d * 16 + k], acc);
    h[(size_t)n * 16 + k] = acc;
}

// 4) layer-1 edge scatter: 16 lanes per edge
__global__ __launch_bounds__(256) void scatter1_kernel(const int* __restrict__ row,
                                                       const int* __restrict__ col,
                                                       const float* __restrict__ dis,
                                                       const float* __restrict__ h,
                                                       float* __restrict__ agg, int E) {
    int t = blockIdx.x * 256 + threadIdx.x;
    int e = t >> 4;
    int k = t & 15;
    if (e >= E) return;
    int r = row[e], c = col[e];
    float w = dis[r] * dis[c];
    atomAddF(&agg[(size_t)c * 16 + k], h[(size_t)r * 16 + k] * w);
}

// 5) h1 = relu(agg1 + h*dis^2 + b1);  g = h1 @ W2  -> [N,2]
__global__ __launch_bounds__(256) void layer2_kernel(const float* __restrict__ agg1,
                                                     const float* __restrict__ h,
                                                     const float* __restrict__ dis,
                                                     const float* __restrict__ b1,
                                                     const float* __restrict__ W2,
                                                     float* __restrict__ g, int N) {
    int n = blockIdx.x * 256 + threadIdx.x;
    if (n >= N) return;
    float d2 = dis[n] * dis[n];
    const float4* ar = (const float4*)(agg1 + (size_t)n * 16);
    const float4* hr = (const float4*)(h + (size_t)n * 16);
    float g0 = 0.0f, g1 = 0.0f;
    #pragma unroll
    for (int q = 0; q < 4; q++) {
        float4 a = ar[q], hh = hr[q];
        float v;
        int k = q * 4;
        v = fmaxf(a.x + hh.x * d2 + b1[k + 0], 0.0f); g0 = fmaf(v, W2[(k+0)*2+0], g0); g1 = fmaf(v, W2[(k+0)*2+1], g1);
        v = fmaxf(a.y + hh.y * d2 + b1[k + 1], 0.0f); g0 = fmaf(v, W2[(k+1)*2+0], g0); g1 = fmaf(v, W2[(k+1)*2+1], g1);
        v = fmaxf(a.z + hh.z * d2 + b1[k + 2], 0.0f); g0 = fmaf(v, W2[(k+2)*2+0], g0); g1 = fmaf(v, W2[(k+2)*2+1], g1);
        v = fmaxf(a.w + hh.w * d2 + b1[k + 3], 0.0f); g0 = fmaf(v, W2[(k+3)*2+0], g0); g1 = fmaf(v, W2[(k+3)*2+1], g1);
    }
    g[(size_t)n * 2 + 0] = g0;
    g[(size_t)n * 2 + 1] = g1;
}

// 6) layer-2 edge scatter: 1 thread per edge, 2 atomics
__global__ __launch_bounds__(256) void scatter2_kernel(const int* __restrict__ row,
                                                       const int* __restrict__ col,
                                                       const float* __restrict__ dis,
                                                       const float* __restrict__ g,
                                                       float* __restrict__ agg2, int E) {
    int e = blockIdx.x * 256 + threadIdx.x;
    if (e >= E) return;
    int r = row[e], c = col[e];
    float w = dis[r] * dis[c];
    float2 gv = *(const float2*)(g + (size_t)r * 2);
    atomAddF(&agg2[(size_t)c * 2 + 0], gv.x * w);
    atomAddF(&agg2[(size_t)c * 2 + 1], gv.y * w);
}

// 7) out = log_softmax(agg2 + g*dis^2 + b2)
__global__ __launch_bounds__(256) void final_kernel(const float* __restrict__ agg2,
                                                    const float* __restrict__ g,
                                                    const float* __restrict__ dis,
                                                    const float* __restrict__ b2,
                                                    float* __restrict__ out, int N) {
    int n = blockIdx.x * 256 + threadIdx.x;
    if (n >= N) return;
    float d2 = dis[n] * dis[n];
    float2 a = *(const float2*)(agg2 + (size_t)n * 2);
    float2 gv = *(const float2*)(g + (size_t)n * 2);
    float o0 = a.x + gv.x * d2 + b2[0];
    float o1 = a.y + gv.y * d2 + b2[1];
    float m = fmaxf(o0, o1);
    float lse = m + logf(expf(o0 - m) + expf(o1 - m));
    float2 r = make_float2(o0 - lse, o1 - lse);
    *(float2*)(out + (size_t)n * 2) = r;
}

extern "C" void kernel_launch(void* const* d_in, const int* in_sizes, int n_in,
                              void* d_out, int out_size, void* d_ws, size_t ws_size,
                              hipStream_t stream) {
    const float* x  = (const float*)d_in[0];
    const int*   ei = (const int*)d_in[1];
    const float* W1 = (const float*)d_in[2];
    const float* b1 = (const float*)d_in[3];
    const float* W2 = (const float*)d_in[4];
    const float* b2 = (const float*)d_in[5];
    float* out = (float*)d_out;

    const int N = in_sizes[0] / DIN;      // 100000
    const int E = in_sizes[1] / 2;        // 3200000
    const int* row = ei;                  // edge_index[0] = sources
    const int* col = ei + E;              // edge_index[1] = targets

    // workspace layout (floats): dis[N] | h[16N] | agg1[16N] | g[2N] | agg2[2N]
    float* dis  = (float*)d_ws;
    float* h    = dis + N;
    float* agg1 = h + (size_t)N * 16;
    float* g    = agg1 + (size_t)N * 16;
    float* agg2 = g + (size_t)N * 2;

    hipMemsetAsync(dis,  0, (size_t)N * 4, stream);
    hipMemsetAsync(agg1, 0, (size_t)N * 16 * 4, stream);
    hipMemsetAsync(agg2, 0, (size_t)N * 2 * 4, stream);

    deg_kernel<<<(E + 255) / 256, 256, 0, stream>>>(col, dis, E);
    dis_kernel<<<(N + 255) / 256, 256, 0, stream>>>(dis, N);
    xw1_kernel<<<(N + 15) / 16, 256, 0, stream>>>(x, W1, h, N);
    scatter1_kernel<<<(int)(((size_t)E * 16 + 255) / 256), 256, 0, stream>>>(row, col, dis, h, agg1, E);
    layer2_kernel<<<(N + 255) / 256, 256, 0, stream>>>(agg1, h, dis, b1, W2, g, N);
    scatter2_kernel<<<(E + 255) / 256, 256, 0, stream>>>(row, col, dis, g, agg2, E);
    final_kernel<<<(N + 255) / 256, 256, 0, stream>>>(agg2, g, dis, b2, out, N);
}

// Round 2
// 647.791 us; speedup vs baseline: 1.2192x; 1.2192x over previous
//
#include <hip/hip_runtime.h>

#define DIN 128
#define SCAN_B 512

// ---------- 1) histogram of targets (= in-degree) ----------
__global__ __launch_bounds__(256) void hist_kernel(const int* __restrict__ col,
                                                   int* __restrict__ cnt, int E) {
    int e = blockIdx.x * 256 + threadIdx.x;
    if (e < E) atomicAdd(&cnt[col[e]], 1);
}

// ---------- 2) two-level exclusive scan over cnt[N] ----------
__global__ __launch_bounds__(SCAN_B) void scan1_kernel(const int* __restrict__ cnt,
                                                       int* __restrict__ off,
                                                       int* __restrict__ bsum, int N) {
    __shared__ int s[SCAN_B];
    int i = blockIdx.x * SCAN_B + threadIdx.x;
    int v = (i < N) ? cnt[i] : 0;
    s[threadIdx.x] = v;
    __syncthreads();
    #pragma unroll
    for (int d = 1; d < SCAN_B; d <<= 1) {
        int t = (threadIdx.x >= d) ? s[threadIdx.x - d] : 0;
        __syncthreads();
        s[threadIdx.x] += t;
        __syncthreads();
    }
    if (i < N) off[i] = s[threadIdx.x] - v;       // exclusive within block
    if (threadIdx.x == SCAN_B - 1) bsum[blockIdx.x] = s[SCAN_B - 1];
}

__global__ __launch_bounds__(256) void scan2_kernel(const int* __restrict__ bsum,
                                                    int* __restrict__ bexc, int nblk) {
    __shared__ int s[256];
    int v = (threadIdx.x < nblk) ? bsum[threadIdx.x] : 0;
    s[threadIdx.x] = v;
    __syncthreads();
    #pragma unroll
    for (int d = 1; d < 256; d <<= 1) {
        int t = (threadIdx.x >= d) ? s[threadIdx.x - d] : 0;
        __syncthreads();
        s[threadIdx.x] += t;
        __syncthreads();
    }
    if (threadIdx.x < nblk) bexc[threadIdx.x] = s[threadIdx.x] - v;
}

// off += block offset; cur = off; dis = rsqrt(deg+1)
__global__ __launch_bounds__(256) void scan3_kernel(const int* __restrict__ cnt,
                                                    int* __restrict__ off,
                                                    int* __restrict__ cur,
                                                    float* __restrict__ dis,
                                                    const int* __restrict__ bexc, int N) {
    int i = blockIdx.x * 256 + threadIdx.x;
    if (i >= N) return;
    int o = off[i] + bexc[i / SCAN_B];
    off[i] = o;
    cur[i] = o;
    dis[i] = rsqrtf((float)cnt[i] + 1.0f);
}

// ---------- 3) CSR placement (counting-sort payload = source id) ----------
__global__ __launch_bounds__(256) void build_kernel(const int* __restrict__ row,
                                                    const int* __restrict__ col,
                                                    int* __restrict__ cur,
                                                    int* __restrict__ srt, int E) {
    int e = blockIdx.x * 256 + threadIdx.x;
    if (e >= E) return;
    int p = atomicAdd(&cur[col[e]], 1);
    srt[p] = row[e];
}

// ---------- 4) hp = (x @ W1) * dis[n]   [N,128]x[128,16] -> [N,16] ----------
__global__ __launch_bounds__(256) void xw1_kernel(const float* __restrict__ x,
                                                  const float* __restrict__ W1,
                                                  const float* __restrict__ dis,
                                                  float* __restrict__ hp, int N) {
    __shared__ float ws[DIN * 16];
    __shared__ float xs[16 * 129];
    int base = blockIdx.x * 16;
    for (int i = threadIdx.x; i < DIN * 16; i += 256) ws[i] = W1[i];
    for (int i = threadIdx.x; i < 16 * DIN; i += 256) {
        int nd = i >> 7, d = i & 127;
        int n = base + nd;
        xs[nd * 129 + d] = (n < N) ? x[(size_t)n * DIN + d] : 0.0f;
    }
    __syncthreads();
    int nd = threadIdx.x >> 4;
    int k  = threadIdx.x & 15;
    int n  = base + nd;
    if (n >= N) return;
    const float* xr = xs + nd * 129;
    float acc = 0.0f;
    #pragma unroll
    for (int d = 0; d < DIN; d++) acc = fmaf(xr[d], ws[d * 16 + k], acc);
    hp[(size_t)n * 16 + k] = acc * dis[n];
}

// ---------- 5) gather layer 1: a1[c] = dis[c] * (hp[c] + sum_{e->c} hp[src]) ----------
__global__ __launch_bounds__(256) void gather1_kernel(const int* __restrict__ srt,
                                                      const int* __restrict__ off,
                                                      const float* __restrict__ dis,
                                                      const float* __restrict__ hp,
                                                      float* __restrict__ a1, int N, int E) {
    int t = blockIdx.x * 256 + threadIdx.x;
    int c = t >> 4;
    int k = t & 15;
    if (c >= N) return;
    int j0 = off[c];
    int j1 = (c == N - 1) ? E : off[c + 1];
    float acc = hp[(size_t)c * 16 + k];          // self-loop (dis[c]*h[c] scaled below)
    for (int j = j0; j < j1; j++) {
        int r = srt[j];
        acc += hp[(size_t)r * 16 + k];
    }
    a1[(size_t)c * 16 + k] = acc * dis[c];
}

// ---------- 6) h1 = relu(a1 + b1); gp = (h1 @ W2) * dis ----------
__global__ __launch_bounds__(256) void layer2_kernel(const float* __restrict__ a1,
                                                     const float* __restrict__ dis,
                                                     const float* __restrict__ b1,
                                                     const float* __restrict__ W2,
                                                     float* __restrict__ gp, int N) {
    int n = blockIdx.x * 256 + threadIdx.x;
    if (n >= N) return;
    const float4* ar = (const float4*)(a1 + (size_t)n * 16);
    float g0 = 0.0f, g1 = 0.0f;
    #pragma unroll
    for (int q = 0; q < 4; q++) {
        float4 a = ar[q];
        float v;
        int k = q * 4;
        v = fmaxf(a.x + b1[k + 0], 0.0f); g0 = fmaf(v, W2[(k+0)*2+0], g0); g1 = fmaf(v, W2[(k+0)*2+1], g1);
        v = fmaxf(a.y + b1[k + 1], 0.0f); g0 = fmaf(v, W2[(k+1)*2+0], g0); g1 = fmaf(v, W2[(k+1)*2+1], g1);
        v = fmaxf(a.z + b1[k + 2], 0.0f); g0 = fmaf(v, W2[(k+2)*2+0], g0); g1 = fmaf(v, W2[(k+2)*2+1], g1);
        v = fmaxf(a.w + b1[k + 3], 0.0f); g0 = fmaf(v, W2[(k+3)*2+0], g0); g1 = fmaf(v, W2[(k+3)*2+1], g1);
    }
    float d = dis[n];
    *(float2*)(gp + (size_t)n * 2) = make_float2(g0 * d, g1 * d);
}

// ---------- 7) gather layer 2 + bias + log_softmax ----------
__global__ __launch_bounds__(256) void gather2_kernel(const int* __restrict__ srt,
                                                      const int* __restrict__ off,
                                                      const float* __restrict__ dis,
                                                      const float* __restrict__ gp,
                                                      const float* __restrict__ b2,
                                                      float* __restrict__ out, int N, int E) {
    int c = blockIdx.x * 256 + threadIdx.x;
    if (c >= N) return;
    int j0 = off[c];
    int j1 = (c == N - 1) ? E : off[c + 1];
    float2 self = *(const float2*)(gp + (size_t)c * 2);
    float a0 = self.x, a1v = self.y;               // self-loop
    for (int j = j0; j < j1; j++) {
        int r = srt[j];
        float2 gv = *(const float2*)(gp + (size_t)r * 2);
        a0 += gv.x;
        a1v += gv.y;
    }
    float d = dis[c];
    float o0 = a0 * d + b2[0];
    float o1 = a1v * d + b2[1];
    float m = fmaxf(o0, o1);
    float lse = m + logf(expf(o0 - m) + expf(o1 - m));
    *(float2*)(out + (size_t)c * 2) = make_float2(o0 - lse, o1 - lse);
}

extern "C" void kernel_launch(void* const* d_in, const int* in_sizes, int n_in,
                              void* d_out, int out_size, void* d_ws, size_t ws_size,
                              hipStream_t stream) {
    const float* x  = (const float*)d_in[0];
    const int*   ei = (const int*)d_in[1];
    const float* W1 = (const float*)d_in[2];
    const float* b1 = (const float*)d_in[3];
    const float* W2 = (const float*)d_in[4];
    const float* b2 = (const float*)d_in[5];
    float* out = (float*)d_out;

    const int N = in_sizes[0] / DIN;      // 100000
    const int E = in_sizes[1] / 2;        // 3200000
    const int* row = ei;                  // sources
    const int* col = ei + E;              // targets
    const int nblk = (N + SCAN_B - 1) / SCAN_B;   // 196

    // workspace layout (4-byte units):
    // cnt[N] | off[N] | cur[N] | dis[N] | srt[E] | hp[16N] | a1[16N] | gp[2N] | bsum[256] | bexc[256]
    int*   cnt  = (int*)d_ws;
    int*   off  = cnt + N;
    int*   cur  = off + N;
    float* dis  = (float*)(cur + N);
    int*   srt  = (int*)(dis + N);
    float* hp   = (float*)(srt + E);
    float* a1   = hp + (size_t)N * 16;
    float* gp   = a1 + (size_t)N * 16;
    int*   bsum = (int*)(gp + (size_t)N * 2);
    int*   bexc = bsum + 256;

    hipMemsetAsync(cnt, 0, (size_t)N * 4, stream);

    hist_kernel <<<(E + 255) / 256, 256, 0, stream>>>(col, cnt, E);
    scan1_kernel<<<nblk, SCAN_B, 0, stream>>>(cnt, off, bsum, N);
    scan2_kernel<<<1, 256, 0, stream>>>(bsum, bexc, nblk);
    scan3_kernel<<<(N + 255) / 256, 256, 0, stream>>>(cnt, off, cur, dis, bexc, N);
    build_kernel<<<(E + 255) / 256, 256, 0, stream>>>(row, col, cur, srt, E);
    xw1_kernel  <<<(N + 15) / 16, 256, 0, stream>>>(x, W1, dis, hp, N);
    gather1_kernel<<<(int)(((size_t)N * 16 + 255) / 256), 256, 0, stream>>>(srt, off, dis, hp, a1, N, E);
    layer2_kernel<<<(N + 255) / 256, 256, 0, stream>>>(a1, dis, b1, W2, gp, N);
    gather2_kernel<<<(N + 255) / 256, 256, 0, stream>>>(srt, off, dis, gp, b2, out, N, E);
}

// Round 3
// 309.509 us; speedup vs baseline: 2.5517x; 2.0930x over previous
//
#include <hip/hip_runtime.h>

#define DIN 128
#define BSH 7                 // log2(targets per bucket)
#define BSIZE 128             // targets per bucket
#define NBMAX 800             // max bucket count (N<=102400)
#define CAP 4480              // slots per bucket region (mean 4096, +6 sigma)
#define CHUNK 8192            // edges per place-WG

// ---------- K0: init per-bucket cursors ----------
__global__ __launch_bounds__(256) void init_kernel(int* __restrict__ cur, int NB) {
    int i = blockIdx.x * 256 + threadIdx.x;
    if (i < NB) cur[i] = i * CAP;
}

// ---------- K1: bucket the edges (LDS-staged, coalesced run writes) ----------
__global__ __launch_bounds__(256) void place_kernel(const int* __restrict__ row,
                                                    const int* __restrict__ col,
                                                    int* __restrict__ cur,
                                                    int* __restrict__ sp, int E, int NB) {
    __shared__ int pk[CHUNK];
    __shared__ unsigned short bkid[CHUNK];
    __shared__ int lcnt[NBMAX], lstart[NBMAX], gofs[NBMAX], lcur[NBMAX];
    __shared__ int sst[256];
    int t = threadIdx.x;
    int e0 = blockIdx.x * CHUNK;
    int cnt = min(CHUNK, E - e0);

    for (int i = t; i < NBMAX; i += 256) { lcnt[i] = 0; lcur[i] = 0; }
    __syncthreads();
    // phase A: count per bucket
    for (int i = t; i < cnt; i += 256)
        atomicAdd(&lcnt[col[e0 + i] >> BSH], 1);
    __syncthreads();
    // exclusive scan lcnt -> lstart (256 threads x 4 elems)
    int b4 = t * 4;
    int v0 = (b4 + 0 < NBMAX) ? lcnt[b4 + 0] : 0;
    int v1 = (b4 + 1 < NBMAX) ? lcnt[b4 + 1] : 0;
    int v2 = (b4 + 2 < NBMAX) ? lcnt[b4 + 2] : 0;
    int v3 = (b4 + 3 < NBMAX) ? lcnt[b4 + 3] : 0;
    int tot = v0 + v1 + v2 + v3;
    sst[t] = tot;
    __syncthreads();
    for (int d = 1; d < 256; d <<= 1) {
        int tmp = (t >= d) ? sst[t - d] : 0;
        __syncthreads();
        sst[t] += tmp;
        __syncthreads();
    }
    int ex = sst[t] - tot;
    if (b4 + 0 < NBMAX) lstart[b4 + 0] = ex;
    if (b4 + 1 < NBMAX) lstart[b4 + 1] = ex + v0;
    if (b4 + 2 < NBMAX) lstart[b4 + 2] = ex + v0 + v1;
    if (b4 + 3 < NBMAX) lstart[b4 + 3] = ex + v0 + v1 + v2;
    __syncthreads();
    // reserve global space: ONE atomic per (wg,bucket)
    for (int b = t; b < NB; b += 256) {
        int c = lcnt[b];
        int gb = c ? atomicAdd(&cur[b], c) : 0;
        gofs[b] = gb - lstart[b];
    }
    __syncthreads();
    // phase B: place into LDS sorted by bucket
    for (int i = t; i < cnt; i += 256) {
        int r  = row[e0 + i];
        int cc = col[e0 + i];
        int b  = cc >> BSH;
        int rk = atomicAdd(&lcur[b], 1);
        int pos = lstart[b] + rk;
        pk[pos]   = ((cc & (BSIZE - 1)) << 17) | r;
        bkid[pos] = (unsigned short)b;
    }
    __syncthreads();
    // phase C: coalesced run copy-out
    for (int i = t; i < cnt; i += 256)
        sp[gofs[bkid[i]] + i] = pk[i];
}

// ---------- K2: exclusive scan of bucket counts -> compact CSR bases ----------
__global__ __launch_bounds__(1024) void bscan_kernel(const int* __restrict__ cur,
                                                     int* __restrict__ bbase, int NB) {
    __shared__ int s[1024];
    int t = threadIdx.x;
    int v = (t < NB) ? (cur[t] - t * CAP) : 0;
    s[t] = v;
    __syncthreads();
    for (int d = 1; d < 1024; d <<= 1) {
        int tmp = (t >= d) ? s[t - d] : 0;
        __syncthreads();
        s[t] += tmp;
        __syncthreads();
    }
    if (t < NB) bbase[t] = s[t] - v;
    if (t == NB - 1) bbase[NB] = s[t];   // == E
}

// ---------- K3: per-bucket LDS counting sort by target; emit srt/off/dis ----------
__global__ __launch_bounds__(256) void bsort_kernel(const int* __restrict__ sp,
                                                    const int* __restrict__ bbase,
                                                    int* __restrict__ srt,
                                                    int* __restrict__ off,
                                                    float* __restrict__ dis, int N) {
    __shared__ int spk[CAP];
    __shared__ int ss[CAP];
    __shared__ int lcnt[BSIZE], lstart[BSIZE], lcur[BSIZE], sc[BSIZE];
    int b = blockIdx.x;
    int t = threadIdx.x;
    int base = bbase[b];
    int cntb = bbase[b + 1] - base;
    const int* src = sp + b * CAP;
    if (t < BSIZE) { lcnt[t] = 0; lcur[t] = 0; }
    __syncthreads();
    for (int i = t; i < cntb; i += 256) {
        int v = src[i];
        spk[i] = v;
        atomicAdd(&lcnt[v >> 17], 1);
    }
    __syncthreads();
    int v = (t < BSIZE) ? lcnt[t] : 0;
    if (t < BSIZE) sc[t] = v;
    __syncthreads();
    for (int d = 1; d < BSIZE; d <<= 1) {
        int tmp = (t < BSIZE && t >= d) ? sc[t - d] : 0;
        __syncthreads();
        if (t < BSIZE) sc[t] += tmp;
        __syncthreads();
    }
    if (t < BSIZE) lstart[t] = sc[t] - v;
    __syncthreads();
    for (int i = t; i < cntb; i += 256) {
        int vv = spk[i];
        int lt = vv >> 17;
        int rk = atomicAdd(&lcur[lt], 1);
        ss[lstart[lt] + rk] = vv & 0x1FFFF;
    }
    __syncthreads();
    for (int i = t; i < cntb; i += 256) srt[base + i] = ss[i];
    if (t < BSIZE) {
        int gt = b * BSIZE + t;
        if (gt < N) {
            off[gt] = base + lstart[t];
            dis[gt] = rsqrtf((float)lcnt[t] + 1.0f);
        }
    }
}

// ---------- K4: hp = (x @ W1) * dis[n] ----------
__global__ __launch_bounds__(256) void xw1_kernel(const float* __restrict__ x,
                                                  const float* __restrict__ W1,
                                                  const float* __restrict__ dis,
                                                  float* __restrict__ hp, int N) {
    __shared__ float ws[DIN * 16];
    __shared__ float xs[16 * 129];
    int base = blockIdx.x * 16;
    for (int i = threadIdx.x; i < DIN * 16; i += 256) ws[i] = W1[i];
    for (int i = threadIdx.x; i < 16 * DIN; i += 256) {
        int nd = i >> 7, d = i & 127;
        int n = base + nd;
        xs[nd * 129 + d] = (n < N) ? x[(size_t)n * DIN + d] : 0.0f;
    }
    __syncthreads();
    int nd = threadIdx.x >> 4;
    int k  = threadIdx.x & 15;
    int n  = base + nd;
    if (n >= N) return;
    const float* xr = xs + nd * 129;
    float acc = 0.0f;
    #pragma unroll
    for (int d = 0; d < DIN; d++) acc = fmaf(xr[d], ws[d * 16 + k], acc);
    hp[(size_t)n * 16 + k] = acc * dis[n];
}

// ---------- K5: gather layer 1 ----------
__global__ __launch_bounds__(256) void gather1_kernel(const int* __restrict__ srt,
                                                      const int* __restrict__ off,
                                                      const float* __restrict__ dis,
                                                      const float* __restrict__ hp,
                                                      float* __restrict__ a1, int N, int E) {
    int t = blockIdx.x * 256 + threadIdx.x;
    int c = t >> 4;
    int k = t & 15;
    if (c >= N) return;
    int j0 = off[c];
    int j1 = (c == N - 1) ? E : off[c + 1];
    float acc = hp[(size_t)c * 16 + k];          // self-loop
    for (int j = j0; j < j1; j++) {
        int r = srt[j];
        acc += hp[(size_t)r * 16 + k];
    }
    a1[(size_t)c * 16 + k] = acc * dis[c];
}

// ---------- K6: h1 = relu(a1 + b1); gp = (h1 @ W2) * dis ----------
__global__ __launch_bounds__(256) void layer2_kernel(const float* __restrict__ a1,
                                                     const float* __restrict__ dis,
                                                     const float* __restrict__ b1,
                                                     const float* __restrict__ W2,
                                                     float* __restrict__ gp, int N) {
    int n = blockIdx.x * 256 + threadIdx.x;
    if (n >= N) return;
    const float4* ar = (const float4*)(a1 + (size_t)n * 16);
    float g0 = 0.0f, g1 = 0.0f;
    #pragma unroll
    for (int q = 0; q < 4; q++) {
        float4 a = ar[q];
        float v;
        int k = q * 4;
        v = fmaxf(a.x + b1[k + 0], 0.0f); g0 = fmaf(v, W2[(k+0)*2+0], g0); g1 = fmaf(v, W2[(k+0)*2+1], g1);
        v = fmaxf(a.y + b1[k + 1], 0.0f); g0 = fmaf(v, W2[(k+1)*2+0], g0); g1 = fmaf(v, W2[(k+1)*2+1], g1);
        v = fmaxf(a.z + b1[k + 2], 0.0f); g0 = fmaf(v, W2[(k+2)*2+0], g0); g1 = fmaf(v, W2[(k+2)*2+1], g1);
        v = fmaxf(a.w + b1[k + 3], 0.0f); g0 = fmaf(v, W2[(k+3)*2+0], g0); g1 = fmaf(v, W2[(k+3)*2+1], g1);
    }
    float d = dis[n];
    *(float2*)(gp + (size_t)n * 2) = make_float2(g0 * d, g1 * d);
}

// ---------- K7: gather layer 2 + bias + log_softmax ----------
__global__ __launch_bounds__(256) void gather2_kernel(const int* __restrict__ srt,
                                                      const int* __restrict__ off,
                                                      const float* __restrict__ dis,
                                                      const float* __restrict__ gp,
                                                      const float* __restrict__ b2,
                                                      float* __restrict__ out, int N, int E) {
    int c = blockIdx.x * 256 + threadIdx.x;
    if (c >= N) return;
    int j0 = off[c];
    int j1 = (c == N - 1) ? E : off[c + 1];
    float2 self = *(const float2*)(gp + (size_t)c * 2);
    float a0 = self.x, a1v = self.y;
    for (int j = j0; j < j1; j++) {
        int r = srt[j];
        float2 gv = *(const float2*)(gp + (size_t)r * 2);
        a0 += gv.x;
        a1v += gv.y;
    }
    float d = dis[c];
    float o0 = a0 * d + b2[0];
    float o1 = a1v * d + b2[1];
    float m = fmaxf(o0, o1);
    float lse = m + logf(expf(o0 - m) + expf(o1 - m));
    *(float2*)(out + (size_t)c * 2) = make_float2(o0 - lse, o1 - lse);
}

extern "C" void kernel_launch(void* const* d_in, const int* in_sizes, int n_in,
                              void* d_out, int out_size, void* d_ws, size_t ws_size,
                              hipStream_t stream) {
    const float* x  = (const float*)d_in[0];
    const int*   ei = (const int*)d_in[1];
    const float* W1 = (const float*)d_in[2];
    const float* b1 = (const float*)d_in[3];
    const float* W2 = (const float*)d_in[4];
    const float* b2 = (const float*)d_in[5];
    float* out = (float*)d_out;

    const int N = in_sizes[0] / DIN;          // 100000
    const int E = in_sizes[1] / 2;            // 3200000
    const int* row = ei;                      // sources
    const int* col = ei + E;                  // targets
    const int NB = (N + BSIZE - 1) / BSIZE;   // 782

    // ws layout (4B units): cur[NBMAX] | bbase[NBMAX+1] | dis[N] | off[N] | srt[E] |
    //                       X: sp[NB*CAP]  (aliased after bsort by hp[16N]|a1[16N]|gp[2N])
    int*   cur   = (int*)d_ws;
    int*   bbase = cur + NBMAX;
    float* dis   = (float*)(bbase + NBMAX + 1);
    int*   off   = (int*)(dis + N);
    int*   srt   = off + N;
    int*   sp    = srt + E;
    float* hp    = (float*)sp;                 // alias: sp dead after bsort
    float* a1    = hp + (size_t)N * 16;
    float* gp    = a1 + (size_t)N * 16;

    init_kernel <<<(NB + 255) / 256, 256, 0, stream>>>(cur, NB);
    place_kernel<<<(E + CHUNK - 1) / CHUNK, 256, 0, stream>>>(row, col, cur, sp, E, NB);
    bscan_kernel<<<1, 1024, 0, stream>>>(cur, bbase, NB);
    bsort_kernel<<<NB, 256, 0, stream>>>(sp, bbase, srt, off, dis, N);
    xw1_kernel  <<<(N + 15) / 16, 256, 0, stream>>>(x, W1, dis, hp, N);
    gather1_kernel<<<(int)(((size_t)N * 16 + 255) / 256), 256, 0, stream>>>(srt, off, dis, hp, a1, N, E);
    layer2_kernel<<<(N + 255) / 256, 256, 0, stream>>>(a1, dis, b1, W2, gp, N);
    gather2_kernel<<<(N + 255) / 256, 256, 0, stream>>>(srt, off, dis, gp, b2, out, N, E);
}